// Round 6
// baseline (173.143 us; speedup 1.0000x reference)
//
#include <hip/hip_runtime.h>
#include <hip/hip_bf16.h>

// inputs (256,128,64) f32, mask (256,128) i32, qparams (4,2,10) f32,
// W (4,256,10) f32, b (4,256) f32.
// out (FLOAT32, per reference output dtype):
//   outputs(256,128,256) ++ hx(128,256) ++ cx(128,256).
#define T_LEN 256
#define BATCH 128
#define NQ 10
#define NG 4
#define HID 256
#define OUT_HX (T_LEN * BATCH * HID)
#define OUT_CX (OUT_HX + BATCH * HID)

// One block per (batch b, hidden half). Phase 1: analytic circuit z-values
// for all (t,g) into LDS. Phase 2: fused gate projection + LSTM scan.
//
// Circuit closed form (validated exactly vs hand statevector algebra at n=2
// general angles + n=3 spot checks, and empirically vs the exact wave-level
// statevector simulator, r4): |psi> = L R1 L R0 |0>,
// R0=⊗RX(phi_k=x_k+th0_k), R1=⊗RX(th1_k), L = C(8,9)...C(0,1) (C(0,1) 1st).
// z_w via 4-state DP over Pauli {I,Z,Y,X} (full angles):
//   step j=w..0: nI=cth_j(cphi_{j+1} vZ - sphi_{j+1} vY); nZ=cth_j vI;
//                nY=sth_j vX; nX=-sth_j(sphi_{j+1} vZ + cphi_{j+1} vY)
//   init w<9: vI=1 start j=w;  w=9: vZ=cth_9, vY=sth_9 start j=8
//   z_w = vI + cphi_0 vZ - sphi_0 vY
__global__ __launch_bounds__(128) void qlstm_kernel(
    const float* __restrict__ inputs,
    const int*  __restrict__ mask,
    const float* __restrict__ qparams,
    const float* __restrict__ W,
    const float* __restrict__ bias,
    float* __restrict__ out)
{
  const int b    = blockIdx.x;     // 0..127
  const int half = blockIdx.y;     // 0..1
  const int tid  = threadIdx.x;    // 0..127
  const int h    = half * 128 + tid;

  __shared__ float zs[T_LEN][NG * NQ];   // 40 KB
  __shared__ float mk[T_LEN];
  __shared__ float th0_s[NG * NQ], cth_s[NG * NQ], sth_s[NG * NQ];

  if (tid < NG * NQ) {
    int g = tid / NQ, k = tid - g * NQ;
    th0_s[tid] = qparams[g * 2 * NQ + k];
    float t1   = qparams[g * 2 * NQ + NQ + k];
    sincosf(t1, &sth_s[tid], &cth_s[tid]);
  }
  for (int t = tid; t < T_LEN; t += 128) mk[t] = (float)mask[t * BATCH + b];
  __syncthreads();

  // ---- phase 1: 1024 circuit instances (t,g) -> zs ----
  for (int inst = tid; inst < T_LEN * NG; inst += 128) {
    int t = inst >> 2, g = inst & 3;
    float cphi[NQ], sphi[NQ];
#pragma unroll
    for (int k = 0; k < NQ; ++k) {
      float x = inputs[(t * BATCH + b) * 64 + k];
      sincosf(x + th0_s[g * NQ + k], &sphi[k], &cphi[k]);
    }
    const float* cth = cth_s + g * NQ;
    const float* sth = sth_s + g * NQ;
#pragma unroll
    for (int w = 0; w < NQ; ++w) {
      float vI, vZ, vY, vX; int js;
      if (w == NQ - 1) { vI = 0.f; vZ = cth[NQ-1]; vY = sth[NQ-1]; vX = 0.f; js = NQ - 2; }
      else             { vI = 1.f; vZ = 0.f; vY = 0.f; vX = 0.f; js = w; }
      for (int j = js; j >= 0; --j) {
        float nI = cth[j] * (cphi[j+1] * vZ - sphi[j+1] * vY);
        float nZ = cth[j] * vI;
        float nY = sth[j] * vX;
        float nX = -sth[j] * (sphi[j+1] * vZ + cphi[j+1] * vY);
        vI = nI; vZ = nZ; vY = nY; vX = nX;
      }
      zs[t][g * NQ + w] = vI + cphi[0] * vZ - sphi[0] * vY;
    }
  }
  __syncthreads();

  // ---- phase 2: gate projection + LSTM scan (one h per thread) ----
  float Wreg[NG * NQ], bg[NG];
#pragma unroll
  for (int g = 0; g < NG; ++g) {
#pragma unroll
    for (int n = 0; n < NQ; ++n)
      Wreg[g * NQ + n] = W[(g * HID + h) * NQ + n];
    bg[g] = bias[g * HID + h];
  }

  float c = 0.f, hv = 0.f;
  for (int t = 0; t < T_LEN; ++t) {
    float pre[NG];
#pragma unroll
    for (int g = 0; g < NG; ++g) {
      float acc = bg[g];
#pragma unroll
      for (int n = 0; n < NQ; ++n)
        acc = fmaf(zs[t][g * NQ + n], Wreg[g * NQ + n], acc);
      pre[g] = acc;
    }
    float m = mk[t], im = 1.f - m;
    float f  = m / (1.f + __expf(-pre[0])) + im;
    float i_ = m / (1.f + __expf(-pre[1]));
    float gg = m * (2.f / (1.f + __expf(-2.f * pre[2])) - 1.f);
    float o  = m / (1.f + __expf(-pre[3])) + im;
    c  = f * c + i_ * gg;
    hv = o * (2.f / (1.f + __expf(-2.f * c)) - 1.f);
    out[t * (BATCH * HID) + b * HID + h] = hv;
  }
  out[OUT_HX + b * HID + h] = hv;
  out[OUT_CX + b * HID + h] = c;
}

extern "C" void kernel_launch(void* const* d_in, const int* in_sizes, int n_in,
                              void* d_out, int out_size, void* d_ws, size_t ws_size,
                              hipStream_t stream)
{
  // identify arrays by unique element counts (order-proof)
  int ii = 0, im = 1, iq = 2, iw = 3, ib = 4;
  for (int i = 0; i < n_in; ++i) {
    switch (in_sizes[i]) {
      case 2097152: ii = i; break;   // inputs (256,128,64)
      case 32768:   im = i; break;   // mask (256,128)
      case 80:      iq = i; break;   // qparams (4,2,10)
      case 10240:   iw = i; break;   // W (4,256,10)
      case 1024:    ib = i; break;   // b (4,256)
      default: break;
    }
  }
  const float* inputs  = (const float*)d_in[ii];
  const int*   mask    = (const int*)d_in[im];
  const float* qparams = (const float*)d_in[iq];
  const float* W       = (const float*)d_in[iw];
  const float* bias    = (const float*)d_in[ib];
  float*       out     = (float*)d_out;

  qlstm_kernel<<<dim3(BATCH, 2), dim3(128), 0, stream>>>(
      inputs, mask, qparams, W, bias, out);
}

// Round 7
// 120.801 us; speedup vs baseline: 1.4333x; 1.4333x over previous
//
#include <hip/hip_runtime.h>

// inputs (256,128,64) f32, mask (256,128) i32, qparams (4,2,10) f32,
// W (4,256,10) f32, b (4,256) f32.
// out f32: outputs(256,128,256) ++ hx(128,256) ++ cx(128,256).
#define T_LEN 256
#define BATCH 128
#define NQ 10
#define NG 4
#define HID 256
#define OUT_HX (T_LEN * BATCH * HID)
#define OUT_CX (OUT_HX + BATCH * HID)

// Block = (b, h-half), 512 threads = 128 chains x 4 gate-lanes.
// Phase 1: analytic circuit z (validated: DP == exact statevector sim, r3/r4
// bit-identical; passed r6 absmax 3.9e-3) for all (t,g) into LDS.
// Phase 2: gate-split LSTM scan. lane = chain*4 + g; each lane computes its
// own gate; shfl_xor(1),(2),(2) lands (f,i,gbar,o) on the g==0 lane with no
// selects; g==0 lane carries (c,h) and stores.
__global__ __launch_bounds__(512) void qlstm_kernel(
    const float* __restrict__ inputs,
    const int*  __restrict__ mask,
    const float* __restrict__ qparams,
    const float* __restrict__ W,
    const float* __restrict__ bias,
    float* __restrict__ out)
{
  const int b    = blockIdx.x;     // 0..127
  const int half = blockIdx.y;     // 0..1
  const int tid  = threadIdx.x;    // 0..511
  const int g    = tid & 3;
  const int ch   = tid >> 2;       // 0..127
  const int h    = half * 128 + ch;

  __shared__ __align__(16) float zs[T_LEN][48];  // gate stride 12 floats; 48KB
  __shared__ float mk[T_LEN];
  __shared__ float th0_s[NG * NQ], cth_s[NG * NQ], sth_s[NG * NQ];

  if (tid < NG * NQ) {
    int gg = tid / NQ, k = tid - gg * NQ;
    th0_s[tid] = qparams[gg * 2 * NQ + k];
    float t1   = qparams[gg * 2 * NQ + NQ + k];
    sth_s[tid] = __sinf(t1);
    cth_s[tid] = __cosf(t1);
  }
  for (int t = tid; t < T_LEN; t += 512) mk[t] = (float)mask[t * BATCH + b];
  __syncthreads();

  // ---- phase 1: 1024 circuit instances (t,g) -> zs (2 per thread) ----
  for (int inst = tid; inst < T_LEN * NG; inst += 512) {
    int t = inst >> 2, gg = inst & 3;
    float cphi[NQ], sphi[NQ];
#pragma unroll
    for (int k = 0; k < NQ; ++k) {
      float ang = inputs[(t * BATCH + b) * 64 + k] + th0_s[gg * NQ + k];
      sphi[k] = __sinf(ang);
      cphi[k] = __cosf(ang);
    }
    const float* cth = cth_s + gg * NQ;
    const float* sth = sth_s + gg * NQ;
#pragma unroll
    for (int w = 0; w < NQ; ++w) {
      float vI, vZ, vY, vX; int js;
      if (w == NQ - 1) { vI = 0.f; vZ = cth[NQ-1]; vY = sth[NQ-1]; vX = 0.f; js = NQ - 2; }
      else             { vI = 1.f; vZ = 0.f; vY = 0.f; vX = 0.f; js = w; }
#pragma unroll
      for (int j = js; j >= 0; --j) {
        float nI = cth[j] * (cphi[j+1] * vZ - sphi[j+1] * vY);
        float nZ = cth[j] * vI;
        float nY = sth[j] * vX;
        float nX = -sth[j] * (sphi[j+1] * vZ + cphi[j+1] * vY);
        vI = nI; vZ = nZ; vY = nY; vX = nX;
      }
      zs[t][gg * 12 + w] = vI + cphi[0] * vZ - sphi[0] * vY;
    }
  }
  __syncthreads();

  // ---- phase 2: gate-split scan ----
  float Wreg[NQ];
#pragma unroll
  for (int n = 0; n < NQ; ++n) Wreg[n] = W[(g * HID + h) * NQ + n];
  float bg = bias[g * HID + h];

  // per-lane gate constants: u = sigma(scale_in * pre); val = m*(a*u+bt) + d*(1-m)
  const float scale_in = (g == 2) ? -2.f : -1.f;   // exp argument multiplier
  const float a_c  = (g == 2) ? 2.f : 1.f;
  const float bt_c = (g == 2) ? -1.f : 0.f;
  const float d_c  = (g == 0 || g == 3) ? 1.f : 0.f;

  const int g12 = g * 12;
  float4 za = *(const float4*)&zs[0][g12];
  float4 zb = *(const float4*)&zs[0][g12 + 4];
  float2 zc = *(const float2*)&zs[0][g12 + 8];
  float mcur = mk[0];

  float c = 0.f, hv = 0.f;
  float* outp = out + b * HID + h;

  for (int t = 0; t < T_LEN; ++t) {
    int tn = (t + 1 < T_LEN) ? t + 1 : t;
    float4 na = *(const float4*)&zs[tn][g12];
    float4 nb = *(const float4*)&zs[tn][g12 + 4];
    float2 nc = *(const float2*)&zs[tn][g12 + 8];
    float mnext = mk[tn];

    float acc0 = fmaf(za.x, Wreg[0], bg);
    acc0 = fmaf(za.y, Wreg[1], acc0);
    acc0 = fmaf(za.z, Wreg[2], acc0);
    acc0 = fmaf(za.w, Wreg[3], acc0);
    acc0 = fmaf(zc.x, Wreg[8], acc0);
    float acc1 = zb.x * Wreg[4];
    acc1 = fmaf(zb.y, Wreg[5], acc1);
    acc1 = fmaf(zb.z, Wreg[6], acc1);
    acc1 = fmaf(zb.w, Wreg[7], acc1);
    acc1 = fmaf(zc.y, Wreg[9], acc1);
    float pre = acc0 + acc1;

    float e = __expf(scale_in * pre);
    float u = __builtin_amdgcn_rcpf(1.f + e);
    float val = fmaf(mcur, fmaf(a_c, u, bt_c), d_c * (1.f - mcur));

    float v1 = __shfl_xor(val, 1, 64);   // gate g^1
    float v2 = __shfl_xor(val, 2, 64);   // gate g^2
    float v3 = __shfl_xor(v1, 2, 64);    // gate g^3

    if (g == 0) {                        // val=f, v1=i, v2=gbar, v3=o
      c = fmaf(val, c, v1 * v2);
      float e2 = __expf(-2.f * c);
      float tc = fmaf(2.f, __builtin_amdgcn_rcpf(1.f + e2), -1.f);
      hv = v3 * tc;
      outp[t * (BATCH * HID)] = hv;
    }
    za = na; zb = nb; zc = nc; mcur = mnext;
  }
  if (g == 0) {
    out[OUT_HX + b * HID + h] = hv;
    out[OUT_CX + b * HID + h] = c;
  }
}

extern "C" void kernel_launch(void* const* d_in, const int* in_sizes, int n_in,
                              void* d_out, int out_size, void* d_ws, size_t ws_size,
                              hipStream_t stream)
{
  // identify arrays by unique element counts (order-proof)
  int ii = 0, im = 1, iq = 2, iw = 3, ib = 4;
  for (int i = 0; i < n_in; ++i) {
    switch (in_sizes[i]) {
      case 2097152: ii = i; break;   // inputs (256,128,64)
      case 32768:   im = i; break;   // mask (256,128)
      case 80:      iq = i; break;   // qparams (4,2,10)
      case 10240:   iw = i; break;   // W (4,256,10)
      case 1024:    ib = i; break;   // b (4,256)
      default: break;
    }
  }
  const float* inputs  = (const float*)d_in[ii];
  const int*   mask    = (const int*)d_in[im];
  const float* qparams = (const float*)d_in[iq];
  const float* W       = (const float*)d_in[iw];
  const float* bias    = (const float*)d_in[ib];
  float*       out     = (float*)d_out;

  qlstm_kernel<<<dim3(BATCH, 2), dim3(512), 0, stream>>>(
      inputs, mask, qparams, W, bias, out);
}